// Round 1
// baseline (744.399 us; speedup 1.0000x reference)
//
#include <hip/hip_runtime.h>

// ---------------------------------------------------------------------------
// WriteMemory: B=512, D_MODEL=2048, H=8, D_MEM=128, M=512
// out = [next_memories (512*512*128) | next_mass (512*512*128)] fp32
// ---------------------------------------------------------------------------

typedef _Float16 half8  __attribute__((ext_vector_type(8)));
typedef _Float16 half4v __attribute__((ext_vector_type(4)));
typedef float    f32x4  __attribute__((ext_vector_type(4)));

#define NB      512          // batch
#define DMODEL  2048
#define NH      8
#define DMEM    128
#define NM      512          // memory slots
#define NMTOT   33554432     // 512*512*128

// ---------------------------------------------------------------------------
// K0a: fp32 -> fp16 convert (vectorized float4 -> half4)
// ---------------------------------------------------------------------------
__global__ void cvt_f32_f16(const float* __restrict__ in, _Float16* __restrict__ out, int n4) {
    int i = blockIdx.x * blockDim.x + threadIdx.x;
    if (i < n4) {
        float4 v = ((const float4*)in)[i];
        half4v o;
        o[0] = (_Float16)v.x; o[1] = (_Float16)v.y;
        o[2] = (_Float16)v.z; o[3] = (_Float16)v.w;
        ((half4v*)out)[i] = o;
    }
}

// ---------------------------------------------------------------------------
// K0b: W [K=2048][N] fp32  ->  Wt [N][2048] fp16  (32x32 LDS tile transpose)
// ---------------------------------------------------------------------------
__global__ void transp_cvt(const float* __restrict__ W, _Float16* __restrict__ Wt, int N) {
    __shared__ float tile[32][33];
    const int k0 = blockIdx.x * 32, n0 = blockIdx.y * 32;
    const int c = threadIdx.x & 31, r0 = threadIdx.x >> 5;
#pragma unroll
    for (int i = 0; i < 4; i++) {
        int r = r0 + i * 8;
        tile[r][c] = W[(size_t)(k0 + r) * N + n0 + c];
    }
    __syncthreads();
#pragma unroll
    for (int i = 0; i < 4; i++) {
        int r = r0 + i * 8;
        Wt[(size_t)(n0 + r) * 2048 + k0 + c] = (_Float16)tile[c][r];
    }
}

// ---------------------------------------------------------------------------
// K0c: aq = elu(addresses)+1 (fp32 + fp16 copies); sigI = sigmoid(interp)
// ---------------------------------------------------------------------------
__global__ void prep_aq(const float* __restrict__ addresses, const float* __restrict__ ilog,
                        float* __restrict__ aqF, _Float16* __restrict__ aqH,
                        float* __restrict__ sigI) {
    int i = blockIdx.x * 256 + threadIdx.x;   // 65536 total
    float a = addresses[i];
    float v = a > 0.f ? a + 1.f : __expf(a);  // elu(x)+1
    aqF[i] = v;
    aqH[i] = (_Float16)v;
    sigI[i] = 1.0f / (1.0f + __expf(-ilog[i]));
}

// ---------------------------------------------------------------------------
// K1: fused GEMM  C[512][3072] over K=2048, fp16 MFMA 16x16x32.
//   n <  1024: ak  = act(key @ W_key + b_key)   -> akF fp32 [512][1024]
//   n >= 1024: v   = values @ W_val + b_val     -> vH  fp16 [512][2048]
// Tiles: BM=64, BN=64, BK=64; 4 waves in 2x2, each 32x32 (2x2 MFMA tiles).
// ---------------------------------------------------------------------------
__global__ void gemm_kv(const _Float16* __restrict__ key16,
                        const _Float16* __restrict__ val16,
                        const _Float16* __restrict__ WkT,
                        const _Float16* __restrict__ WvT,
                        const float* __restrict__ b_key,
                        const float* __restrict__ b_val,
                        float* __restrict__ akF,
                        _Float16* __restrict__ vH) {
    __shared__ _Float16 As[64][72];   // +8 pad: conflict-free ds_read_b128
    __shared__ _Float16 Bs[64][72];

    const int t = threadIdx.x;
    const int m0 = blockIdx.x * 64;
    const int n0 = blockIdx.y * 64;
    const bool isK = (n0 < 1024);
    const _Float16* aSrc = isK ? key16 : val16;
    const _Float16* bSrc = isK ? (WkT + (size_t)n0 * 2048)
                               : (WvT + (size_t)(n0 - 1024) * 2048);

    const int w = t >> 6, lane = t & 63;
    const int col = lane & 15, q = lane >> 4;
    const int wm = (w & 1) * 32, wn = (w >> 1) * 32;

    f32x4 acc[2][2];
#pragma unroll
    for (int i = 0; i < 2; i++)
#pragma unroll
        for (int j = 0; j < 2; j++) acc[i][j] = (f32x4){0.f, 0.f, 0.f, 0.f};

    for (int k0 = 0; k0 < 2048; k0 += 64) {
        __syncthreads();
#pragma unroll
        for (int i = 0; i < 2; i++) {
            int s = t + 256 * i, row = s >> 3, ch = s & 7;
            *(uint4*)&As[row][ch * 8] =
                *(const uint4*)(aSrc + (size_t)(m0 + row) * 2048 + k0 + ch * 8);
            *(uint4*)&Bs[row][ch * 8] =
                *(const uint4*)(bSrc + (size_t)row * 2048 + k0 + ch * 8);
        }
        __syncthreads();
#pragma unroll
        for (int ks = 0; ks < 2; ks++) {
            half8 a0 = *(const half8*)&As[wm + col][ks * 32 + q * 8];
            half8 a1 = *(const half8*)&As[wm + 16 + col][ks * 32 + q * 8];
            half8 b0 = *(const half8*)&Bs[wn + col][ks * 32 + q * 8];
            half8 b1 = *(const half8*)&Bs[wn + 16 + col][ks * 32 + q * 8];
            acc[0][0] = __builtin_amdgcn_mfma_f32_16x16x32_f16(a0, b0, acc[0][0], 0, 0, 0);
            acc[0][1] = __builtin_amdgcn_mfma_f32_16x16x32_f16(a0, b1, acc[0][1], 0, 0, 0);
            acc[1][0] = __builtin_amdgcn_mfma_f32_16x16x32_f16(a1, b0, acc[1][0], 0, 0, 0);
            acc[1][1] = __builtin_amdgcn_mfma_f32_16x16x32_f16(a1, b1, acc[1][1], 0, 0, 0);
        }
    }
    // epilogue: C/D layout col=lane&15, row=(lane>>4)*4+reg  [m89/m91-verified]
#pragma unroll
    for (int mt = 0; mt < 2; mt++) {
#pragma unroll
        for (int nt = 0; nt < 2; nt++) {
            int n = n0 + wn + nt * 16 + col;
#pragma unroll
            for (int r = 0; r < 4; r++) {
                int m = m0 + wm + mt * 16 + q * 4 + r;
                float x = acc[mt][nt][r];
                if (isK) {
                    x += b_key[n];
                    akF[(size_t)m * 1024 + n] = (x > 0.f) ? (x + 1.f) : __expf(x);
                } else {
                    int nn = n - 1024;
                    x += b_val[nn];
                    vH[(size_t)m * 2048 + nn] = (_Float16)x;
                }
            }
        }
    }
}

// ---------------------------------------------------------------------------
// K3: per-batch mega-fused kernel (one block per b, 256 threads = 4 waves).
//  A: build matT[e][d] = fp16(matrix[b][d][e]) in LDS (rank-8 outer product),
//     nrm[d] = sum_h ak[b][h][d]
//  B: sDen[m] = 1 / (aq[m]·nrm + 1e-5)   (coalesced + wave shuffle reduce)
//  C: numerator tiles via MFMA (aq fp16 from global, matT from LDS);
//     wave w owns e in [32w,32w+32) U [128+32w,128+32w+32) so each lane holds
//     matching (update, write_logit) pairs -> blend + store, no materialization.
// LDS total = 4096+4096+512+2048+69632 = 80384 B -> 2 blocks/CU.
// ---------------------------------------------------------------------------
__global__ __launch_bounds__(256, 2) void fused_mem(
    const float* __restrict__ akF,        // [512][1024] fp32
    const _Float16* __restrict__ vH,      // [512][2048] fp16
    const _Float16* __restrict__ aqH,     // [512][128]  fp16
    const float* __restrict__ aqF,        // [512][128]  fp32
    const float* __restrict__ sigI,       // [512][128]  fp32
    const float* __restrict__ memories,   // [512][512][128]
    const float* __restrict__ write_mass, // [512][512][128]
    const unsigned char* __restrict__ bmask,
    float* __restrict__ out) {
    __shared__ float    sA[NH][DMEM];      // 4 KB
    __shared__ _Float16 sV[NH][256];       // 4 KB
    __shared__ float    sNrm[DMEM];        // 0.5 KB
    __shared__ float    sDen[NM];          // 2 KB
    __shared__ _Float16 matT[256][DMEM + 8]; // 68 KB, +8 pad breaks conflicts

    const int b = blockIdx.x;
    const int t = threadIdx.x;
    const int w = t >> 6, lane = t & 63;
    const int col = lane & 15, q = lane >> 4;

    // ---- stage ak[b], v[b] ----
    ((float4*)&sA[0][0])[t] = ((const float4*)(akF + (size_t)b * 1024))[t];
    ((uint4*)&sV[0][0])[t]  = ((const uint4*)(vH + (size_t)b * 2048))[t];
    __syncthreads();

    // ---- normalizer ----
    if (t < 128) {
        float s = 0.f;
#pragma unroll
        for (int h = 0; h < NH; h++) s += sA[h][t];
        sNrm[t] = s;
    }

    // ---- matT build: thread owns d0 (4 wide) x e-strips of 8 ----
    {
        const int d0 = (t & 31) * 4;
        const int ebase = (t >> 5) * 8;
        float a[NH][4];
#pragma unroll
        for (int h = 0; h < NH; h++) {
            float4 av = *(const float4*)&sA[h][d0];
            a[h][0] = av.x; a[h][1] = av.y; a[h][2] = av.z; a[h][3] = av.w;
        }
#pragma unroll
        for (int eq = 0; eq < 4; eq++) {
            const int e0 = ebase + 64 * eq;
            float vf[NH][8];
#pragma unroll
            for (int h = 0; h < NH; h++) {
                half8 vv = *(const half8*)&sV[h][e0];
#pragma unroll
                for (int e = 0; e < 8; e++) vf[h][e] = (float)vv[e];
            }
#pragma unroll
            for (int e = 0; e < 8; e++) {
                float c0 = 0.f, c1 = 0.f, c2 = 0.f, c3 = 0.f;
#pragma unroll
                for (int h = 0; h < NH; h++) {
                    float vv = vf[h][e];
                    c0 += a[h][0] * vv; c1 += a[h][1] * vv;
                    c2 += a[h][2] * vv; c3 += a[h][3] * vv;
                }
                half4v o;
                o[0] = (_Float16)c0; o[1] = (_Float16)c1;
                o[2] = (_Float16)c2; o[3] = (_Float16)c3;
                *(half4v*)&matT[e0 + e][d0] = o;
            }
        }
    }
    __syncthreads();

    // ---- denominators (coalesced aq row reads, 32-lane shuffle reduce) ----
    {
        const int l32 = lane & 31;
        const int hh = lane >> 5;
        const float4 nv = *(const float4*)&sNrm[l32 * 4];
        for (int pass = 0; pass < 64; pass++) {
            int m = pass * 8 + w * 2 + hh;
            float4 qv = *(const float4*)(aqF + (size_t)m * 128 + l32 * 4);
            float s = qv.x * nv.x + qv.y * nv.y + qv.z * nv.z + qv.w * nv.w;
            s += __shfl_xor(s, 1);  s += __shfl_xor(s, 2);  s += __shfl_xor(s, 4);
            s += __shfl_xor(s, 8);  s += __shfl_xor(s, 16);
            if (l32 == 0) sDen[m] = 1.0f / (s + 1e-5f);
        }
    }
    __syncthreads();

    // ---- phase C: MFMA + fused epilogue ----
    const float wfscale = (bmask[b] != 0) ? 0.0f : 0.7f;  // mask -> wf=0 -> passthrough
    const size_t obase = (size_t)b * (NM * DMEM);

    for (int mc = 0; mc < 8; mc++) {
        const int mbase = mc * 64;
        f32x4 acc[4][4];
#pragma unroll
        for (int i = 0; i < 4; i++)
#pragma unroll
            for (int j = 0; j < 4; j++) acc[i][j] = (f32x4){0.f, 0.f, 0.f, 0.f};

#pragma unroll
        for (int ks = 0; ks < 4; ks++) {
            half8 bfr[4];
#pragma unroll
            for (int nt = 0; nt < 4; nt++) {
                int eb = 32 * w + (nt & 1) * 16 + (nt >> 1) * 128;
                bfr[nt] = *(const half8*)&matT[eb + col][ks * 32 + q * 8];
            }
#pragma unroll
            for (int mt = 0; mt < 4; mt++) {
                const half8 af = *(const half8*)(aqH + (size_t)(mbase + mt * 16 + col) * 128
                                                 + ks * 32 + q * 8);
#pragma unroll
                for (int nt = 0; nt < 4; nt++)
                    acc[mt][nt] = __builtin_amdgcn_mfma_f32_16x16x32_f16(af, bfr[nt],
                                                                         acc[mt][nt], 0, 0, 0);
            }
        }

#pragma unroll
        for (int mt = 0; mt < 4; mt++) {
            const int mrow = mbase + mt * 16 + q * 4;
            float rc[4];
#pragma unroll
            for (int r = 0; r < 4; r++) rc[r] = sDen[mrow + r];
#pragma unroll
            for (int p = 0; p < 2; p++) {
                const int ec = 32 * w + p * 16 + col;
#pragma unroll
                for (int r = 0; r < 4; r++) {
                    const size_t gi = obase + (size_t)(mrow + r) * 128 + ec;
                    const float mem = memories[gi];
                    const float wms = write_mass[gi];
                    const float si = sigI[(mrow + r) * 128 + ec];
                    const float upd = acc[mt][p][r] * rc[r];
                    const float wl = acc[mt][p + 2][r] * rc[r];
                    const float wpb = 1.0f / (1.0f + __expf(-wl));
                    const float wf = wfscale * wpb * si;
                    out[gi] = mem + wf * (upd - mem);          // mem*(1-wf)+upd*wf
                    out[NMTOT + gi] = wms + wf;
                }
            }
        }
    }
}

// ---------------------------------------------------------------------------
extern "C" void kernel_launch(void* const* d_in, const int* in_sizes, int n_in,
                              void* d_out, int out_size, void* d_ws, size_t ws_size,
                              hipStream_t stream) {
    const float* key        = (const float*)d_in[0];
    const float* values     = (const float*)d_in[1];
    const float* memories   = (const float*)d_in[2];
    const float* write_mass = (const float*)d_in[3];
    const unsigned char* bm = (const unsigned char*)d_in[4];
    const float* W_key      = (const float*)d_in[5];
    const float* b_key      = (const float*)d_in[6];
    const float* W_val      = (const float*)d_in[7];
    const float* b_val      = (const float*)d_in[8];
    const float* addresses  = (const float*)d_in[9];
    const float* ilog       = (const float*)d_in[10];
    float* out = (float*)d_out;

    char* ws = (char*)d_ws;
    _Float16* key16 = (_Float16*)ws;  ws += (size_t)512 * 2048 * 2;
    _Float16* val16 = (_Float16*)ws;  ws += (size_t)512 * 2048 * 2;
    _Float16* WkT   = (_Float16*)ws;  ws += (size_t)1024 * 2048 * 2;
    _Float16* WvT   = (_Float16*)ws;  ws += (size_t)2048 * 2048 * 2;
    float*    akF   = (float*)ws;     ws += (size_t)512 * 1024 * 4;
    _Float16* vH    = (_Float16*)ws;  ws += (size_t)512 * 2048 * 2;
    float*    aqF   = (float*)ws;     ws += (size_t)512 * 128 * 4;
    _Float16* aqH   = (_Float16*)ws;  ws += (size_t)512 * 128 * 2;
    float*    sigI  = (float*)ws;     ws += (size_t)512 * 128 * 4;

    cvt_f32_f16<<<1024, 256, 0, stream>>>(key, key16, 262144);
    cvt_f32_f16<<<1024, 256, 0, stream>>>(values, val16, 262144);
    transp_cvt<<<dim3(64, 32), 256, 0, stream>>>(W_key, WkT, 1024);
    transp_cvt<<<dim3(64, 64), 256, 0, stream>>>(W_val, WvT, 2048);
    prep_aq<<<256, 256, 0, stream>>>(addresses, ilog, aqF, aqH, sigI);
    gemm_kv<<<dim3(8, 48), 256, 0, stream>>>(key16, val16, WkT, WvT, b_key, b_val, akF, vH);
    fused_mem<<<512, 256, 0, stream>>>(akF, vH, aqH, aqF, sigI, memories, write_mass, bm, out);
}

// Round 2
// 628.303 us; speedup vs baseline: 1.1848x; 1.1848x over previous
//
#include <hip/hip_runtime.h>

// ---------------------------------------------------------------------------
// WriteMemory: B=512, D_MODEL=2048, H=8, D_MEM=128, M=512
// out = [next_memories (512*512*128) | next_mass (512*512*128)] fp32
// ---------------------------------------------------------------------------

typedef _Float16 half8  __attribute__((ext_vector_type(8)));
typedef _Float16 half4v __attribute__((ext_vector_type(4)));
typedef float    f32x4  __attribute__((ext_vector_type(4)));

#define NB      512
#define DMODEL  2048
#define NH      8
#define DMEM    128
#define NM      512
#define NMTOT   33554432     // 512*512*128

__device__ __forceinline__ f32x4 ntload4(const float* p) {
    return __builtin_nontemporal_load((const f32x4*)p);
}
__device__ __forceinline__ void ntstore4(float* p, f32x4 v) {
    __builtin_nontemporal_store(v, (f32x4*)p);
}

// ---------------------------------------------------------------------------
// K0a: fp32 -> fp16 convert
// ---------------------------------------------------------------------------
__global__ void cvt_f32_f16(const float* __restrict__ in, _Float16* __restrict__ out, int n4) {
    int i = blockIdx.x * blockDim.x + threadIdx.x;
    if (i < n4) {
        float4 v = ((const float4*)in)[i];
        half4v o;
        o[0] = (_Float16)v.x; o[1] = (_Float16)v.y;
        o[2] = (_Float16)v.z; o[3] = (_Float16)v.w;
        ((half4v*)out)[i] = o;
    }
}

// ---------------------------------------------------------------------------
// K0b: W [K=2048][N] fp32 -> Wt [N][2048] fp16
// ---------------------------------------------------------------------------
__global__ void transp_cvt(const float* __restrict__ W, _Float16* __restrict__ Wt, int N) {
    __shared__ float tile[32][33];
    const int k0 = blockIdx.x * 32, n0 = blockIdx.y * 32;
    const int c = threadIdx.x & 31, r0 = threadIdx.x >> 5;
#pragma unroll
    for (int i = 0; i < 4; i++) {
        int r = r0 + i * 8;
        tile[r][c] = W[(size_t)(k0 + r) * N + n0 + c];
    }
    __syncthreads();
#pragma unroll
    for (int i = 0; i < 4; i++) {
        int r = r0 + i * 8;
        Wt[(size_t)(n0 + r) * 2048 + k0 + c] = (_Float16)tile[c][r];
    }
}

// ---------------------------------------------------------------------------
// K0c: aq = elu(addresses)+1; sigI = sigmoid(interp)
// ---------------------------------------------------------------------------
__global__ void prep_aq(const float* __restrict__ addresses, const float* __restrict__ ilog,
                        float* __restrict__ aqF, _Float16* __restrict__ aqH,
                        float* __restrict__ sigI) {
    int i = blockIdx.x * 256 + threadIdx.x;
    float a = addresses[i];
    float v = a > 0.f ? a + 1.f : __expf(a);
    aqF[i] = v;
    aqH[i] = (_Float16)v;
    sigI[i] = 1.0f / (1.0f + __expf(-ilog[i]));
}

// ---------------------------------------------------------------------------
// K1: fused GEMM C[512][3072] over K=2048, fp16 MFMA 16x16x32.
// Double-buffered LDS + register prefetch: one barrier per K-iter,
// global loads for k+1 in flight during compute of k.
// ---------------------------------------------------------------------------
__global__ __launch_bounds__(256) void gemm_kv(
        const _Float16* __restrict__ key16,
        const _Float16* __restrict__ val16,
        const _Float16* __restrict__ WkT,
        const _Float16* __restrict__ WvT,
        const float* __restrict__ b_key,
        const float* __restrict__ b_val,
        float* __restrict__ akF,
        _Float16* __restrict__ vH) {
    __shared__ _Float16 As[2][64][72];
    __shared__ _Float16 Bs[2][64][72];

    const int t = threadIdx.x;
    const int m0 = blockIdx.x * 64;
    const int n0 = blockIdx.y * 64;
    const bool isK = (n0 < 1024);
    const _Float16* aSrc = isK ? key16 : val16;
    const _Float16* bSrc = isK ? (WkT + (size_t)n0 * 2048)
                               : (WvT + (size_t)(n0 - 1024) * 2048);

    const int w = t >> 6, lane = t & 63;
    const int col = lane & 15, q = lane >> 4;
    const int wm = (w & 1) * 32, wn = (w >> 1) * 32;

    // staging map: slots s = t, t+256 -> row = s>>3, chunk = s&7 (16B)
    const int row0 = t >> 3, ch = t & 7;
    const int row1 = (t + 256) >> 3;

    f32x4 acc[2][2];
#pragma unroll
    for (int i = 0; i < 2; i++)
#pragma unroll
        for (int j = 0; j < 2; j++) acc[i][j] = (f32x4){0.f, 0.f, 0.f, 0.f};

    // prefetch k0 = 0
    uint4 ra0 = *(const uint4*)(aSrc + (size_t)(m0 + row0) * 2048 + ch * 8);
    uint4 ra1 = *(const uint4*)(aSrc + (size_t)(m0 + row1) * 2048 + ch * 8);
    uint4 rb0 = *(const uint4*)(bSrc + (size_t)row0 * 2048 + ch * 8);
    uint4 rb1 = *(const uint4*)(bSrc + (size_t)row1 * 2048 + ch * 8);

    int buf = 0;
    for (int k0 = 0; k0 < 2048; k0 += 64) {
        *(uint4*)&As[buf][row0][ch * 8] = ra0;
        *(uint4*)&As[buf][row1][ch * 8] = ra1;
        *(uint4*)&Bs[buf][row0][ch * 8] = rb0;
        *(uint4*)&Bs[buf][row1][ch * 8] = rb1;
        if (k0 + 64 < 2048) {
            const int kn = k0 + 64;
            ra0 = *(const uint4*)(aSrc + (size_t)(m0 + row0) * 2048 + kn + ch * 8);
            ra1 = *(const uint4*)(aSrc + (size_t)(m0 + row1) * 2048 + kn + ch * 8);
            rb0 = *(const uint4*)(bSrc + (size_t)row0 * 2048 + kn + ch * 8);
            rb1 = *(const uint4*)(bSrc + (size_t)row1 * 2048 + kn + ch * 8);
        }
        __syncthreads();
#pragma unroll
        for (int ks = 0; ks < 2; ks++) {
            half8 a0 = *(const half8*)&As[buf][wm + col][ks * 32 + q * 8];
            half8 a1 = *(const half8*)&As[buf][wm + 16 + col][ks * 32 + q * 8];
            half8 b0 = *(const half8*)&Bs[buf][wn + col][ks * 32 + q * 8];
            half8 b1 = *(const half8*)&Bs[buf][wn + 16 + col][ks * 32 + q * 8];
            acc[0][0] = __builtin_amdgcn_mfma_f32_16x16x32_f16(a0, b0, acc[0][0], 0, 0, 0);
            acc[0][1] = __builtin_amdgcn_mfma_f32_16x16x32_f16(a0, b1, acc[0][1], 0, 0, 0);
            acc[1][0] = __builtin_amdgcn_mfma_f32_16x16x32_f16(a1, b0, acc[1][0], 0, 0, 0);
            acc[1][1] = __builtin_amdgcn_mfma_f32_16x16x32_f16(a1, b1, acc[1][1], 0, 0, 0);
        }
        buf ^= 1;
    }
    // epilogue: C/D layout col=lane&15, row=(lane>>4)*4+reg
#pragma unroll
    for (int mt = 0; mt < 2; mt++) {
#pragma unroll
        for (int nt = 0; nt < 2; nt++) {
            int n = n0 + wn + nt * 16 + col;
#pragma unroll
            for (int r = 0; r < 4; r++) {
                int m = m0 + wm + mt * 16 + q * 4 + r;
                float x = acc[mt][nt][r];
                if (isK) {
                    x += b_key[n];
                    akF[(size_t)m * 1024 + n] = (x > 0.f) ? (x + 1.f) : __expf(x);
                } else {
                    int nn = n - 1024;
                    x += b_val[nn];
                    vH[(size_t)m * 2048 + nn] = (_Float16)x;
                }
            }
        }
    }
}

// ---------------------------------------------------------------------------
// K3: per-batch mega-fused kernel. 1024 threads = 16 waves, 1 block/CU.
//  A: matT[e][d] fp16 in LDS (rank-8 outer product) + nrm[d]
//  B: sDen[m] = 1/(aq[m].nrm + 1e-5)
//  C: wave w -> e-slice (w&3)*32 (update + paired logit at +128),
//     m-blocks (w>>2) and (w>>2)+4. After MFMA, per-wave LDS transpose of
//     each 16x32 tile so lanes own 4 consecutive e -> float4 nontemporal
//     loads of memories/write_mass and float4 stores of both outputs.
// LDS: 69632 + 40960 + 4096 + 4096 + 512 + 2048 = 121344 B -> 1 block/CU.
// ---------------------------------------------------------------------------
__global__ __launch_bounds__(1024, 1) void fused_mem(
    const float* __restrict__ akF,        // [512][1024]
    const _Float16* __restrict__ vH,      // [512][2048]
    const _Float16* __restrict__ aqH,     // [512][128]
    const float* __restrict__ aqF,        // [512][128]
    const float* __restrict__ sigI,       // [512][128]
    const float* __restrict__ memories,   // [512][512][128]
    const float* __restrict__ write_mass, // [512][512][128]
    const unsigned char* __restrict__ bmask,
    float* __restrict__ out) {
    __shared__ _Float16 matT[256][DMEM + 8];   // 69632 B
    __shared__ float    xtile[16][16][40];     // 40960 B, per-wave scratch
    __shared__ float    sA[NH][DMEM];          // 4096 B
    __shared__ _Float16 sV[NH][256];           // 4096 B
    __shared__ float    sNrm[DMEM];            // 512 B
    __shared__ float    sDen[NM];              // 2048 B

    const int b = blockIdx.x;
    const int t = threadIdx.x;
    const int w = t >> 6, lane = t & 63;
    const int col = lane & 15, q = lane >> 4;

    // ---- stage ak[b], v[b] ----
    if (t < 256) {
        ((float4*)&sA[0][0])[t] = ((const float4*)(akF + (size_t)b * 1024))[t];
        ((uint4*)&sV[0][0])[t]  = ((const uint4*)(vH + (size_t)b * 2048))[t];
    }
    __syncthreads();

    // ---- normalizer ----
    if (t < 128) {
        float s = 0.f;
#pragma unroll
        for (int h = 0; h < NH; h++) s += sA[h][t];
        sNrm[t] = s;
    }

    // ---- matT build: 1024 threads, each 4 d x 8 e ----
    {
        const int d0 = (t & 31) * 4;
        const int e0 = (t >> 5) * 8;
        float c[8][4];
#pragma unroll
        for (int e = 0; e < 8; e++)
#pragma unroll
            for (int d = 0; d < 4; d++) c[e][d] = 0.f;
#pragma unroll
        for (int h = 0; h < NH; h++) {
            float4 av = *(const float4*)&sA[h][d0];
            half8 vv = *(const half8*)&sV[h][e0];
#pragma unroll
            for (int e = 0; e < 8; e++) {
                float vf = (float)vv[e];
                c[e][0] += av.x * vf; c[e][1] += av.y * vf;
                c[e][2] += av.z * vf; c[e][3] += av.w * vf;
            }
        }
#pragma unroll
        for (int e = 0; e < 8; e++) {
            half4v o;
            o[0] = (_Float16)c[e][0]; o[1] = (_Float16)c[e][1];
            o[2] = (_Float16)c[e][2]; o[3] = (_Float16)c[e][3];
            *(half4v*)&matT[e0 + e][d0] = o;
        }
    }
    __syncthreads();

    // ---- denominators: 16 passes, 32 m per pass ----
    {
        const int l32 = lane & 31;
        const int hh = lane >> 5;
        const float4 nv = *(const float4*)&sNrm[l32 * 4];
#pragma unroll 4
        for (int pass = 0; pass < 16; pass++) {
            int m = pass * 32 + w * 2 + hh;
            float4 qv = *(const float4*)(aqF + (size_t)m * 128 + l32 * 4);
            float s = qv.x * nv.x + qv.y * nv.y + qv.z * nv.z + qv.w * nv.w;
            s += __shfl_xor(s, 1);  s += __shfl_xor(s, 2);  s += __shfl_xor(s, 4);
            s += __shfl_xor(s, 8);  s += __shfl_xor(s, 16);
            if (l32 == 0) sDen[m] = 1.0f / (s + 1e-5f);
        }
    }
    __syncthreads();

    // ---- phase C ----
    const float wfscale = (bmask[b] != 0) ? 0.0f : 0.7f;
    const size_t obase = (size_t)b * (NM * DMEM);
    float (*tile)[40] = xtile[w];
    const int slice = w & 3;                 // e-slice of 32
    const int eg0 = 32 * slice + (lane & 3) * 4;
    const int mloc = lane >> 2;

    for (int it = 0; it < 2; it++) {
        const int mbase = ((w >> 2) + it * 4) * 64;
        f32x4 acc[4][4];
#pragma unroll
        for (int i = 0; i < 4; i++)
#pragma unroll
            for (int j = 0; j < 4; j++) acc[i][j] = (f32x4){0.f, 0.f, 0.f, 0.f};

#pragma unroll
        for (int ks = 0; ks < 4; ks++) {
            half8 bfr[4];
#pragma unroll
            for (int nt = 0; nt < 4; nt++) {
                int eb = 32 * slice + (nt & 1) * 16 + (nt >> 1) * 128;
                bfr[nt] = *(const half8*)&matT[eb + col][ks * 32 + q * 8];
            }
#pragma unroll
            for (int mt = 0; mt < 4; mt++) {
                const half8 af = *(const half8*)(aqH + (size_t)(mbase + mt * 16 + col) * 128
                                                 + ks * 32 + q * 8);
#pragma unroll
                for (int nt = 0; nt < 4; nt++)
                    acc[mt][nt] = __builtin_amdgcn_mfma_f32_16x16x32_f16(af, bfr[nt],
                                                                         acc[mt][nt], 0, 0, 0);
            }
        }

#pragma unroll
        for (int mt = 0; mt < 4; mt++) {
            // transpose update tile (16 m x 32 e) via per-wave scratch
#pragma unroll
            for (int r = 0; r < 4; r++) {
                tile[q * 4 + r][col]      = acc[mt][0][r];
                tile[q * 4 + r][16 + col] = acc[mt][1][r];
            }
            __builtin_amdgcn_wave_barrier();
            f32x4 u0 = *(const f32x4*)&tile[mloc][(lane & 3) * 4];
            f32x4 u1 = *(const f32x4*)&tile[mloc][(lane & 3) * 4 + 16];
            __builtin_amdgcn_wave_barrier();
            // transpose logit tile
#pragma unroll
            for (int r = 0; r < 4; r++) {
                tile[q * 4 + r][col]      = acc[mt][2][r];
                tile[q * 4 + r][16 + col] = acc[mt][3][r];
            }
            __builtin_amdgcn_wave_barrier();
            f32x4 g0 = *(const f32x4*)&tile[mloc][(lane & 3) * 4];
            f32x4 g1 = *(const f32x4*)&tile[mloc][(lane & 3) * 4 + 16];
            __builtin_amdgcn_wave_barrier();

            const int mglob = mbase + mt * 16 + mloc;
            const float rc = sDen[mglob];
#pragma unroll
            for (int cch = 0; cch < 2; cch++) {
                const int eg = eg0 + cch * 16;
                const size_t gi = obase + (size_t)mglob * 128 + eg;
                const f32x4 u = cch ? u1 : u0;
                const f32x4 g = cch ? g1 : g0;
                const f32x4 mem = ntload4(memories + gi);
                const f32x4 wms = ntload4(write_mass + gi);
                const f32x4 si  = *(const f32x4*)(sigI + (size_t)mglob * 128 + eg);
                f32x4 o1, o2;
#pragma unroll
                for (int j = 0; j < 4; j++) {
                    const float upd = u[j] * rc;
                    const float wl  = g[j] * rc;
                    const float wpb = 1.0f / (1.0f + __expf(-wl));
                    const float wf  = wfscale * wpb * si[j];
                    o1[j] = mem[j] + wf * (upd - mem[j]);
                    o2[j] = wms[j] + wf;
                }
                ntstore4(out + gi, o1);
                ntstore4(out + NMTOT + gi, o2);
            }
        }
    }
}

// ---------------------------------------------------------------------------
extern "C" void kernel_launch(void* const* d_in, const int* in_sizes, int n_in,
                              void* d_out, int out_size, void* d_ws, size_t ws_size,
                              hipStream_t stream) {
    const float* key        = (const float*)d_in[0];
    const float* values     = (const float*)d_in[1];
    const float* memories   = (const float*)d_in[2];
    const float* write_mass = (const float*)d_in[3];
    const unsigned char* bm = (const unsigned char*)d_in[4];
    const float* W_key      = (const float*)d_in[5];
    const float* b_key      = (const float*)d_in[6];
    const float* W_val      = (const float*)d_in[7];
    const float* b_val      = (const float*)d_in[8];
    const float* addresses  = (const float*)d_in[9];
    const float* ilog       = (const float*)d_in[10];
    float* out = (float*)d_out;

    char* ws = (char*)d_ws;
    _Float16* key16 = (_Float16*)ws;  ws += (size_t)512 * 2048 * 2;
    _Float16* val16 = (_Float16*)ws;  ws += (size_t)512 * 2048 * 2;
    _Float16* WkT   = (_Float16*)ws;  ws += (size_t)1024 * 2048 * 2;
    _Float16* WvT   = (_Float16*)ws;  ws += (size_t)2048 * 2048 * 2;
    float*    akF   = (float*)ws;     ws += (size_t)512 * 1024 * 4;
    _Float16* vH    = (_Float16*)ws;  ws += (size_t)512 * 2048 * 2;
    float*    aqF   = (float*)ws;     ws += (size_t)512 * 128 * 4;
    _Float16* aqH   = (_Float16*)ws;  ws += (size_t)512 * 128 * 2;
    float*    sigI  = (float*)ws;     ws += (size_t)512 * 128 * 4;

    cvt_f32_f16<<<1024, 256, 0, stream>>>(key, key16, 262144);
    cvt_f32_f16<<<1024, 256, 0, stream>>>(values, val16, 262144);
    transp_cvt<<<dim3(64, 32), 256, 0, stream>>>(W_key, WkT, 1024);
    transp_cvt<<<dim3(64, 64), 256, 0, stream>>>(W_val, WvT, 2048);
    prep_aq<<<256, 256, 0, stream>>>(addresses, ilog, aqF, aqH, sigI);
    gemm_kv<<<dim3(8, 48), 256, 0, stream>>>(key16, val16, WkT, WvT, b_key, b_val, akF, vH);
    fused_mem<<<512, 1024, 0, stream>>>(akF, vH, aqH, aqF, sigI, memories, write_mass, bm, out);
}